// Round 1
// baseline (716.978 us; speedup 1.0000x reference)
//
#include <hip/hip_runtime.h>
#include <hip/hip_bf16.h>

typedef unsigned short ushort_t;
typedef __attribute__((ext_vector_type(8))) short short8;
typedef __attribute__((ext_vector_type(8))) unsigned short ushort8;
typedef __attribute__((ext_vector_type(4))) float f32x4;

__device__ __forceinline__ ushort_t f2bf(float f) {
  union { float f; unsigned int u; } c; c.f = f;
  unsigned int u = c.u;
  return (ushort_t)((u + 0x7fffu + ((u >> 16) & 1u)) >> 16);
}

__device__ __forceinline__ void gload_lds16(const void* g, void* l) {
  __builtin_amdgcn_global_load_lds(
      (__attribute__((address_space(1))) void*)(void*)g,
      (__attribute__((address_space(3))) void*)l, 16, 0, 0);
}

// ---------------- LayerNorm: f32 in -> bf16 out, D=512, one row per wave ----
__global__ __launch_bounds__(256) void ln_kernel(
    const float* __restrict__ x, const float* __restrict__ g,
    const float* __restrict__ be, ushort_t* __restrict__ out)
{
  const int lane = threadIdx.x & 63, wid = threadIdx.x >> 6;
  const size_t row = (size_t)blockIdx.x * 4 + wid;
  const float* xr = x + row * 512 + lane * 8;
  float4 v0 = *(const float4*)xr;
  float4 v1 = *(const float4*)(xr + 4);
  float vv[8] = {v0.x,v0.y,v0.z,v0.w,v1.x,v1.y,v1.z,v1.w};
  float s = 0;
#pragma unroll
  for (int e = 0; e < 8; ++e) s += vv[e];
#pragma unroll
  for (int o = 1; o < 64; o <<= 1) s += __shfl_xor(s, o);
  float mu = s * (1.0f/512.0f);
  float sq = 0;
#pragma unroll
  for (int e = 0; e < 8; ++e) { float d = vv[e]-mu; sq += d*d; }
#pragma unroll
  for (int o = 1; o < 64; o <<= 1) sq += __shfl_xor(sq, o);
  float rinv = rsqrtf(sq * (1.0f/512.0f) + 1e-5f);
  const float* gp = g + lane*8; const float* bp = be + lane*8;
  float4 ga = *(const float4*)gp, gb = *(const float4*)(gp+4);
  float4 ba = *(const float4*)bp, bb4 = *(const float4*)(bp+4);
  float gg[8] = {ga.x,ga.y,ga.z,ga.w,gb.x,gb.y,gb.z,gb.w};
  float bb[8] = {ba.x,ba.y,ba.z,ba.w,bb4.x,bb4.y,bb4.z,bb4.w};
  ushort8 o8;
#pragma unroll
  for (int e = 0; e < 8; ++e) o8[e] = f2bf((vv[e]-mu)*rinv*gg[e] + bb[e]);
  *(ushort8*)(out + row*512 + lane*8) = o8;
}

// ---------------- Weight transpose + bf16 convert: in (K,N) -> out (N,K) ----
__global__ __launch_bounds__(256) void wt_kernel(
    const float* __restrict__ w, ushort_t* __restrict__ wT, int K, int N)
{
  int id = blockIdx.x * 256 + threadIdx.x;
  if (id >= K * N) return;
  int n = id / K, kk = id - n * K;
  wT[id] = f2bf(w[(size_t)kk * N + n]);
}

// ---------------- Rel-table prep: pad to 240 rows (bf16), rel_v^T, C0 -------
__global__ __launch_bounds__(256) void prep_rel_kernel(
    const float* __restrict__ rq, const float* __restrict__ rk,
    const float* __restrict__ rv,
    ushort_t* __restrict__ rqp, ushort_t* __restrict__ rkp,
    ushort_t* __restrict__ rvT, float* __restrict__ C0)
{
  int id = blockIdx.x * 256 + threadIdx.x;
  if (id < 240*64) {
    int r = id >> 6, d = id & 63;
    rqp[id] = (r < 225) ? f2bf(rq[r*64+d]) : (ushort_t)0;
    rkp[id] = (r < 225) ? f2bf(rk[r*64+d]) : (ushort_t)0;
  }
  if (id < 64*256) {
    int d = id >> 8, r = id & 255;
    rvT[id] = (r < 225) ? f2bf(rv[r*64+d]) : (ushort_t)0;
  }
  if (id < 225) {
    float s = 0;
    for (int d = 0; d < 64; ++d) s += rq[id*64+d]*rk[id*64+d];
    C0[id] = s;
  }
}

// ---------------- bf16 GEMM: C = A(MxK) * Bt(NxK)^T, 128x128 tile, BK=64 ----
// EPI 0: scatter to q/k/vT buffers   EPI 1/3: +bias +resid -> f32
// EPI 2: relu(+bias) -> bf16
template<int EPI>
__global__ __launch_bounds__(256) void gemm_kernel(
    const ushort_t* __restrict__ A, const ushort_t* __restrict__ Bt,
    int M, int N, int K,
    const float* __restrict__ bias, const float* __restrict__ resid,
    float* __restrict__ outf, ushort_t* __restrict__ outb,
    ushort_t* __restrict__ qb, ushort_t* __restrict__ kb,
    ushort_t* __restrict__ vtb)
{
  __shared__ ushort_t lds[32768];   // 2 buf x (A 16KB + B 16KB)
  const int tid = threadIdx.x, lane = tid & 63, wid = tid >> 6;
  const int m0 = blockIdx.x * 128, n0 = blockIdx.y * 128;
  const int l15 = lane & 15, lh = lane >> 4;
  const int wm = wid >> 1, wn = wid & 1;

  f32x4 acc[4][4] = {};
  const int NT = K >> 6;

  auto stage = [&](int buf, int kt) {
    const int k0 = kt << 6;
#pragma unroll
    for (int p = 0; p < 4; ++p) {
      const int lofs = p*4096 + wid*1024;               // byte offset in half
      const int row = (lofs + lane*16) >> 7;            // 0..127
      const int sc = ((lane & 7) ^ (row & 7)) << 3;     // swizzled src col
      gload_lds16(A  + (size_t)(m0 + row) * K + (k0 + sc),
                  &lds[buf*16384 + (lofs >> 1)]);
      gload_lds16(Bt + (size_t)(n0 + row) * K + (k0 + sc),
                  &lds[buf*16384 + 8192 + (lofs >> 1)]);
    }
  };

  stage(0, 0);
  __syncthreads();
  for (int t = 0; t < NT; ++t) {
    if (t + 1 < NT) stage((t+1) & 1, t+1);
    const ushort_t* Ab = &lds[(t&1)*16384];
    const ushort_t* Bb = Ab + 8192;
#pragma unroll
    for (int kh = 0; kh < 2; ++kh) {
      const int slotk = kh*4 + lh;
      short8 af[4], bf[4];
#pragma unroll
      for (int mi = 0; mi < 4; ++mi) {
        int row = wm*64 + mi*16 + l15;
        af[mi] = *(const short8*)((const char*)Ab + row*128 + ((slotk ^ (row&7))<<4));
      }
#pragma unroll
      for (int ni = 0; ni < 4; ++ni) {
        int row = wn*64 + ni*16 + l15;
        bf[ni] = *(const short8*)((const char*)Bb + row*128 + ((slotk ^ (row&7))<<4));
      }
#pragma unroll
      for (int mi = 0; mi < 4; ++mi)
#pragma unroll
        for (int ni = 0; ni < 4; ++ni)
          acc[mi][ni] = __builtin_amdgcn_mfma_f32_16x16x32_bf16(
              af[mi], bf[ni], acc[mi][ni], 0, 0, 0);
    }
    __syncthreads();
  }

#pragma unroll
  for (int mi = 0; mi < 4; ++mi)
#pragma unroll
    for (int ni = 0; ni < 4; ++ni)
#pragma unroll
      for (int r = 0; r < 4; ++r) {
        const int grow = m0 + wm*64 + mi*16 + lh*4 + r;
        const int gcol = n0 + wn*64 + ni*16 + l15;
        const float v = acc[mi][ni][r];
        if constexpr (EPI == 0) {
          const int sel = gcol >> 9, c5 = gcol & 511;
          const int hh = c5 >> 6, d = c5 & 63;
          const size_t bh = (size_t)((grow >> 6) * 8 + hh);
          const int i = grow & 63;
          const ushort_t bv = f2bf(v);
          if (sel == 0)      qb[(bh<<12) + i*64 + d] = bv;
          else if (sel == 1) kb[(bh<<12) + i*64 + d] = bv;
          else               vtb[(bh<<12) + d*64 + i] = bv;
        } else if constexpr (EPI == 2) {
          float t2 = v + bias[gcol];
          outb[(size_t)grow * N + gcol] = f2bf(t2 > 0.0f ? t2 : 0.0f);
        } else {
          const size_t o = (size_t)grow * N + gcol;
          outf[o] = v + bias[gcol] + resid[o];
        }
      }
}

// ---------------- Fused relative attention, one block per (b,h) ------------
__global__ __launch_bounds__(256) void attn_kernel(
    const ushort_t* __restrict__ qb, const ushort_t* __restrict__ kb,
    const ushort_t* __restrict__ vtb,
    const ushort_t* __restrict__ rkp, const ushort_t* __restrict__ rqp,
    const ushort_t* __restrict__ rvT, const float* __restrict__ C0,
    ushort_t* __restrict__ attn_out)
{
  __shared__ float logits[4096];    // 16KB
  __shared__ ushort_t attnS[4096];  // 8KB  (xor-swizzled rows, 128B stride)
  __shared__ ushort_t S[16384];     // 32KB (xor-swizzled rows, 512B stride)
  const int tid = threadIdx.x, lane = tid & 63, wid = tid >> 6;
  const int bh = blockIdx.x;
  const ushort_t* q  = qb  + (size_t)bh * 4096;
  const ushort_t* k  = kb  + (size_t)bh * 4096;
  const ushort_t* vT = vtb + (size_t)bh * 4096;
  const int l15 = lane & 15, lh = lane >> 4;

  {  // zero S
    short8 z = {};
#pragma unroll
    for (int p = 0; p < 8; ++p) *(short8*)&S[(p*256 + tid) * 8] = z;
  }

  // P1: logits = q @ k^T
  {
    f32x4 acc1[4] = {};
#pragma unroll
    for (int kh = 0; kh < 2; ++kh) {
      const int kbase = kh*32 + lh*8;
      short8 a = *(const short8*)(q + (wid*16 + l15)*64 + kbase);
#pragma unroll
      for (int ni = 0; ni < 4; ++ni) {
        short8 b = *(const short8*)(k + (ni*16 + l15)*64 + kbase);
        acc1[ni] = __builtin_amdgcn_mfma_f32_16x16x32_bf16(a, b, acc1[ni], 0,0,0);
      }
    }
#pragma unroll
    for (int ni = 0; ni < 4; ++ni)
#pragma unroll
      for (int r = 0; r < 4; ++r)
        logits[(wid*16 + lh*4 + r)*64 + ni*16 + l15] = acc1[ni][r];
  }
  __syncthreads();

  // P2: += q_i . rel_k[r], scattered via inverse idx
  {
    f32x4 acc2[15] = {};
#pragma unroll
    for (int kh = 0; kh < 2; ++kh) {
      const int kbase = kh*32 + lh*8;
      short8 a = *(const short8*)(q + (wid*16 + l15)*64 + kbase);
#pragma unroll
      for (int nc = 0; nc < 15; ++nc) {
        short8 b = *(const short8*)(rkp + (nc*16 + l15)*64 + kbase);
        acc2[nc] = __builtin_amdgcn_mfma_f32_16x16x32_bf16(a, b, acc2[nc], 0,0,0);
      }
    }
#pragma unroll
    for (int nc = 0; nc < 15; ++nc)
#pragma unroll
      for (int r = 0; r < 4; ++r) {
        const int i = wid*16 + lh*4 + r;
        const int rr = nc*16 + l15;
        if (rr < 225) {
          const int dx = rr / 15, dy = rr - dx*15;
          const int xj = (i >> 3) - dx + 7, yj = (i & 7) - dy + 7;
          if ((unsigned)xj < 8u && (unsigned)yj < 8u)
            logits[i*64 + xj*8 + yj] += acc2[nc][r];
        }
      }
  }
  __syncthreads();

  // P3: += k_j . rel_q[r], scattered via inverse idx
  {
    f32x4 acc3[15] = {};
#pragma unroll
    for (int kh = 0; kh < 2; ++kh) {
      const int kbase = kh*32 + lh*8;
      short8 a = *(const short8*)(k + (wid*16 + l15)*64 + kbase);
#pragma unroll
      for (int nc = 0; nc < 15; ++nc) {
        short8 b = *(const short8*)(rqp + (nc*16 + l15)*64 + kbase);
        acc3[nc] = __builtin_amdgcn_mfma_f32_16x16x32_bf16(a, b, acc3[nc], 0,0,0);
      }
    }
#pragma unroll
    for (int nc = 0; nc < 15; ++nc)
#pragma unroll
      for (int r = 0; r < 4; ++r) {
        const int j = wid*16 + lh*4 + r;
        const int rr = nc*16 + l15;
        if (rr < 225) {
          const int dx = rr / 15, dy = rr - dx*15;
          const int xi = (j >> 3) + dx - 7, yi = (j & 7) + dy - 7;
          if ((unsigned)xi < 8u && (unsigned)yi < 8u)
            logits[(xi*8 + yi)*64 + j] += acc3[nc][r];
        }
      }
  }
  __syncthreads();

  // P4: softmax (+C0, *scale); write attn (bf16) and scatter S
  {
    const int i = tid >> 2, qq = tid & 3;
    const int xi = i >> 3, yi = i & 7;
    float vals[16]; float m = -1e30f;
#pragma unroll
    for (int jj = 0; jj < 16; ++jj) {
      const int j = qq*16 + jj;
      const int rr = (xi - (j>>3) + 7)*15 + (yi - (j&7) + 7);
      float v = (logits[i*64 + j] + C0[rr]) * 0.125f;
      vals[jj] = v; m = fmaxf(m, v);
    }
    m = fmaxf(m, __shfl_xor(m, 1));
    m = fmaxf(m, __shfl_xor(m, 2));
    float s = 0;
#pragma unroll
    for (int jj = 0; jj < 16; ++jj) { float e = __expf(vals[jj]-m); vals[jj] = e; s += e; }
    s += __shfl_xor(s, 1); s += __shfl_xor(s, 2);
    const float inv = 1.0f / s;
#pragma unroll
    for (int jj = 0; jj < 16; ++jj) {
      const int j = qq*16 + jj;
      const ushort_t pb = f2bf(vals[jj]*inv);
      *(ushort_t*)((char*)attnS + i*128 + (((j>>3) ^ (i&7))<<4) + ((j&7)<<1)) = pb;
      const int rr = (xi - (j>>3) + 7)*15 + (yi - (j&7) + 7);
      *(ushort_t*)((char*)S + i*512 + (((rr>>3) ^ (i&7))<<4) + ((rr&7)<<1)) = pb;
    }
  }
  __syncthreads();

  // P5: out = attn @ v^T^T + S @ rel_v^T
  {
    f32x4 acco[4] = {};
    const int row = wid*16 + l15;
#pragma unroll
    for (int kh = 0; kh < 2; ++kh) {
      const int kbase = kh*32 + lh*8;
      short8 a = *(const short8*)((const char*)attnS + row*128 + (((kbase>>3) ^ (row&7))<<4));
#pragma unroll
      for (int ni = 0; ni < 4; ++ni) {
        short8 b = *(const short8*)(vT + (ni*16 + l15)*64 + kbase);
        acco[ni] = __builtin_amdgcn_mfma_f32_16x16x32_bf16(a, b, acco[ni], 0,0,0);
      }
    }
#pragma unroll
    for (int ks = 0; ks < 8; ++ks) {
      const int kbase = ks*32 + lh*8;
      short8 a = *(const short8*)((const char*)S + row*512 + ((((kbase>>3)) ^ (row&7))<<4));
#pragma unroll
      for (int ni = 0; ni < 4; ++ni) {
        short8 b = *(const short8*)(rvT + (ni*16 + l15)*256 + kbase);
        acco[ni] = __builtin_amdgcn_mfma_f32_16x16x32_bf16(a, b, acco[ni], 0,0,0);
      }
    }
    const int b_idx = bh >> 3, hh = bh & 7;
#pragma unroll
    for (int ni = 0; ni < 4; ++ni)
#pragma unroll
      for (int r = 0; r < 4; ++r) {
        const int i = wid*16 + lh*4 + r;
        const int d = ni*16 + l15;
        attn_out[((size_t)(b_idx*64 + i))*512 + hh*64 + d] = f2bf(acco[ni][r]);
      }
  }
}

// ---------------------------------------------------------------------------
extern "C" void kernel_launch(void* const* d_in, const int* in_sizes, int n_in,
                              void* d_out, int out_size, void* d_ws, size_t ws_size,
                              hipStream_t stream)
{
  (void)in_sizes; (void)n_in; (void)out_size; (void)ws_size;
  const float* x     = (const float*)d_in[0];
  const float* w_qkv = (const float*)d_in[1];
  const float* w_proj= (const float*)d_in[2];
  const float* b_proj= (const float*)d_in[3];
  const float* w1    = (const float*)d_in[4];
  const float* b1    = (const float*)d_in[5];
  const float* w2    = (const float*)d_in[6];
  const float* b2    = (const float*)d_in[7];
  const float* g1    = (const float*)d_in[8];
  const float* be1   = (const float*)d_in[9];
  const float* g2    = (const float*)d_in[10];
  const float* be2   = (const float*)d_in[11];
  const float* rel_q = (const float*)d_in[12];
  const float* rel_k = (const float*)d_in[13];
  const float* rel_v = (const float*)d_in[14];

  char* ws = (char*)d_ws;
  const size_t MB = 1ull << 20;
  ushort_t* h      = (ushort_t*)(ws);            // 32MiB (reused as h2)
  ushort_t* qb     = (ushort_t*)(ws + 32*MB);
  ushort_t* kb     = (ushort_t*)(ws + 64*MB);
  ushort_t* vtb    = (ushort_t*)(ws + 96*MB);
  ushort_t* attn_o = (ushort_t*)(ws + 128*MB);
  ushort_t* ff     = (ushort_t*)(ws + 32*MB);    // aliases qb..attn_o (dead)
  float*    x_mid  = (float*)(ws + 160*MB);      // 64MiB
  char* wreg = ws + 224*MB;
  ushort_t* wqkvT = (ushort_t*)(wreg);
  ushort_t* wprojT= (ushort_t*)(wreg + 1572864);
  ushort_t* w1T   = (ushort_t*)(wreg + 2097152);
  ushort_t* w2T   = (ushort_t*)(wreg + 4194304);
  ushort_t* rkp   = (ushort_t*)(wreg + 6291456);
  ushort_t* rqp   = (ushort_t*)(wreg + 6322176);
  ushort_t* rvT   = (ushort_t*)(wreg + 6352896);
  float*    C0    = (float*)(wreg + 6385664);

  wt_kernel<<<(512*1536+255)/256, 256, 0, stream>>>(w_qkv, wqkvT, 512, 1536);
  wt_kernel<<<(512*512+255)/256, 256, 0, stream>>>(w_proj, wprojT, 512, 512);
  wt_kernel<<<(512*2048+255)/256, 256, 0, stream>>>(w1, w1T, 512, 2048);
  wt_kernel<<<(2048*512+255)/256, 256, 0, stream>>>(w2, w2T, 2048, 512);
  prep_rel_kernel<<<64, 256, 0, stream>>>(rel_q, rel_k, rel_v, rqp, rkp, rvT, C0);

  ln_kernel<<<8192, 256, 0, stream>>>(x, g1, be1, h);
  gemm_kernel<0><<<dim3(256,12), 256, 0, stream>>>(h, wqkvT, 32768, 1536, 512,
      nullptr, nullptr, nullptr, nullptr, qb, kb, vtb);
  attn_kernel<<<4096, 256, 0, stream>>>(qb, kb, vtb, rkp, rqp, rvT, C0, attn_o);
  gemm_kernel<1><<<dim3(256,4), 256, 0, stream>>>(attn_o, wprojT, 32768, 512, 512,
      b_proj, x, x_mid, nullptr, nullptr, nullptr, nullptr);
  ln_kernel<<<8192, 256, 0, stream>>>(x_mid, g2, be2, h);
  gemm_kernel<2><<<dim3(256,16), 256, 0, stream>>>(h, w1T, 32768, 2048, 512,
      b1, nullptr, nullptr, ff, nullptr, nullptr, nullptr);
  gemm_kernel<3><<<dim3(256,4), 256, 0, stream>>>(ff, w2T, 32768, 512, 2048,
      b2, x_mid, (float*)d_out, nullptr, nullptr, nullptr, nullptr);
}

// Round 2
// 653.722 us; speedup vs baseline: 1.0968x; 1.0968x over previous
//
#include <hip/hip_runtime.h>
#include <hip/hip_bf16.h>

typedef unsigned short ushort_t;
typedef __attribute__((ext_vector_type(8))) short short8;
typedef __attribute__((ext_vector_type(8))) unsigned short ushort8;
typedef __attribute__((ext_vector_type(4))) float f32x4;

__device__ __forceinline__ ushort_t f2bf(float f) {
  union { float f; unsigned int u; } c; c.f = f;
  unsigned int u = c.u;
  return (ushort_t)((u + 0x7fffu + ((u >> 16) & 1u)) >> 16);
}

__device__ __forceinline__ void gload_lds16(const void* g, void* l) {
  __builtin_amdgcn_global_load_lds(
      (__attribute__((address_space(1))) void*)(void*)g,
      (__attribute__((address_space(3))) void*)l, 16, 0, 0);
}

// ---------------- LayerNorm: f32 in -> bf16 out, D=512, one row per wave ----
__global__ __launch_bounds__(256) void ln_kernel(
    const float* __restrict__ x, const float* __restrict__ g,
    const float* __restrict__ be, ushort_t* __restrict__ out)
{
  const int lane = threadIdx.x & 63, wid = threadIdx.x >> 6;
  const size_t row = (size_t)blockIdx.x * 4 + wid;
  const float* xr = x + row * 512 + lane * 8;
  float4 v0 = *(const float4*)xr;
  float4 v1 = *(const float4*)(xr + 4);
  float vv[8] = {v0.x,v0.y,v0.z,v0.w,v1.x,v1.y,v1.z,v1.w};
  float s = 0;
#pragma unroll
  for (int e = 0; e < 8; ++e) s += vv[e];
#pragma unroll
  for (int o = 1; o < 64; o <<= 1) s += __shfl_xor(s, o);
  float mu = s * (1.0f/512.0f);
  float sq = 0;
#pragma unroll
  for (int e = 0; e < 8; ++e) { float d = vv[e]-mu; sq += d*d; }
#pragma unroll
  for (int o = 1; o < 64; o <<= 1) sq += __shfl_xor(sq, o);
  float rinv = rsqrtf(sq * (1.0f/512.0f) + 1e-5f);
  const float* gp = g + lane*8; const float* bp = be + lane*8;
  float4 ga = *(const float4*)gp, gb = *(const float4*)(gp+4);
  float4 ba = *(const float4*)bp, bb4 = *(const float4*)(bp+4);
  float gg[8] = {ga.x,ga.y,ga.z,ga.w,gb.x,gb.y,gb.z,gb.w};
  float bb[8] = {ba.x,ba.y,ba.z,ba.w,bb4.x,bb4.y,bb4.z,bb4.w};
  ushort8 o8;
#pragma unroll
  for (int e = 0; e < 8; ++e) o8[e] = f2bf((vv[e]-mu)*rinv*gg[e] + bb[e]);
  *(ushort8*)(out + row*512 + lane*8) = o8;
}

// ---------------- Weight transpose + bf16 convert: in (K,N) -> out (N,K) ----
__global__ __launch_bounds__(256) void wt_kernel(
    const float* __restrict__ w, ushort_t* __restrict__ wT, int K, int N)
{
  int id = blockIdx.x * 256 + threadIdx.x;
  if (id >= K * N) return;
  int n = id / K, kk = id - n * K;
  wT[id] = f2bf(w[(size_t)kk * N + n]);
}

// ---------------- Rel-table prep: pad to 240 rows (bf16), rel_v^T, C0 -------
__global__ __launch_bounds__(256) void prep_rel_kernel(
    const float* __restrict__ rq, const float* __restrict__ rk,
    const float* __restrict__ rv,
    ushort_t* __restrict__ rqp, ushort_t* __restrict__ rkp,
    ushort_t* __restrict__ rvT, float* __restrict__ C0)
{
  int id = blockIdx.x * 256 + threadIdx.x;
  if (id < 240*64) {
    int r = id >> 6, d = id & 63;
    rqp[id] = (r < 225) ? f2bf(rq[r*64+d]) : (ushort_t)0;
    rkp[id] = (r < 225) ? f2bf(rk[r*64+d]) : (ushort_t)0;
  }
  if (id < 64*256) {
    int d = id >> 8, r = id & 255;
    rvT[id] = (r < 225) ? f2bf(rv[r*64+d]) : (ushort_t)0;
  }
  if (id < 225) {
    float s = 0;
    for (int d = 0; d < 64; ++d) s += rq[id*64+d]*rk[id*64+d];
    C0[id] = s;
  }
}

// ---------------- bf16 GEMM: C = A(MxK) * Bt(NxK)^T, 128x128 tile, BK=64 ----
template<int EPI>
__global__ __launch_bounds__(256) void gemm_kernel(
    const ushort_t* __restrict__ A, const ushort_t* __restrict__ Bt,
    int M, int N, int K,
    const float* __restrict__ bias, const float* __restrict__ resid,
    float* __restrict__ outf, ushort_t* __restrict__ outb,
    ushort_t* __restrict__ qb, ushort_t* __restrict__ kb,
    ushort_t* __restrict__ vtb)
{
  __shared__ ushort_t lds[32768];   // 2 buf x (A 16KB + B 16KB)
  const int tid = threadIdx.x, lane = tid & 63, wid = tid >> 6;
  const int m0 = blockIdx.x * 128, n0 = blockIdx.y * 128;
  const int l15 = lane & 15, lh = lane >> 4;
  const int wm = wid >> 1, wn = wid & 1;

  f32x4 acc[4][4] = {};
  const int NT = K >> 6;

  auto stage = [&](int buf, int kt) {
    const int k0 = kt << 6;
#pragma unroll
    for (int p = 0; p < 4; ++p) {
      const int lofs = p*4096 + wid*1024;               // byte offset in half
      const int row = (lofs + lane*16) >> 7;            // 0..127
      const int sc = ((lane & 7) ^ (row & 7)) << 3;     // swizzled src col
      gload_lds16(A  + (size_t)(m0 + row) * K + (k0 + sc),
                  &lds[buf*16384 + (lofs >> 1)]);
      gload_lds16(Bt + (size_t)(n0 + row) * K + (k0 + sc),
                  &lds[buf*16384 + 8192 + (lofs >> 1)]);
    }
  };

  stage(0, 0);
  __syncthreads();
  for (int t = 0; t < NT; ++t) {
    if (t + 1 < NT) stage((t+1) & 1, t+1);
    const ushort_t* Ab = &lds[(t&1)*16384];
    const ushort_t* Bb = Ab + 8192;
#pragma unroll
    for (int kh = 0; kh < 2; ++kh) {
      const int slotk = kh*4 + lh;
      short8 af[4], bf[4];
#pragma unroll
      for (int mi = 0; mi < 4; ++mi) {
        int row = wm*64 + mi*16 + l15;
        af[mi] = *(const short8*)((const char*)Ab + row*128 + ((slotk ^ (row&7))<<4));
      }
#pragma unroll
      for (int ni = 0; ni < 4; ++ni) {
        int row = wn*64 + ni*16 + l15;
        bf[ni] = *(const short8*)((const char*)Bb + row*128 + ((slotk ^ (row&7))<<4));
      }
#pragma unroll
      for (int mi = 0; mi < 4; ++mi)
#pragma unroll
        for (int ni = 0; ni < 4; ++ni)
          acc[mi][ni] = __builtin_amdgcn_mfma_f32_16x16x32_bf16(
              af[mi], bf[ni], acc[mi][ni], 0, 0, 0);
    }
    __syncthreads();
  }

#pragma unroll
  for (int mi = 0; mi < 4; ++mi)
#pragma unroll
    for (int ni = 0; ni < 4; ++ni)
#pragma unroll
      for (int r = 0; r < 4; ++r) {
        const int grow = m0 + wm*64 + mi*16 + lh*4 + r;
        const int gcol = n0 + wn*64 + ni*16 + l15;
        const float v = acc[mi][ni][r];
        if constexpr (EPI == 0) {
          const int sel = gcol >> 9, c5 = gcol & 511;
          const int hh = c5 >> 6, d = c5 & 63;
          const size_t bh = (size_t)((grow >> 6) * 8 + hh);
          const int i = grow & 63;
          const ushort_t bv = f2bf(v);
          if (sel == 0)      qb[(bh<<12) + i*64 + d] = bv;
          else if (sel == 1) kb[(bh<<12) + i*64 + d] = bv;
          else               vtb[(bh<<12) + d*64 + i] = bv;
        } else if constexpr (EPI == 2) {
          float t2 = v + bias[gcol];
          outb[(size_t)grow * N + gcol] = f2bf(t2 > 0.0f ? t2 : 0.0f);
        } else {
          const size_t o = (size_t)grow * N + gcol;
          outf[o] = v + bias[gcol] + resid[o];
        }
      }
}

// ---------------- Fused relative attention, one block per (b,h) ------------
// LDS (40960B, aliased):
//   phases 1-4read : logits [64][65] f32 @ 0 (16640B), C0s @ 16640 (900B)
//   after BAR3     : attnS  [64]x128B swz @ 0 (8KB), S [64]x512B swz @ 8192 (32KB)
__global__ __launch_bounds__(256, 4) void attn_kernel(
    const ushort_t* __restrict__ qb, const ushort_t* __restrict__ kb,
    const ushort_t* __restrict__ vtb,
    const ushort_t* __restrict__ rkp, const ushort_t* __restrict__ rqp,
    const ushort_t* __restrict__ rvT, const float* __restrict__ C0,
    ushort_t* __restrict__ attn_out)
{
  __shared__ char smem[40960];
  float* logits  = (float*)smem;            // stride 65 floats
  float* C0s     = (float*)(smem + 16640);
  char*  attnSB  = smem;
  char*  Sb      = smem + 8192;
  const int tid = threadIdx.x, lane = tid & 63, wid = tid >> 6;
  const int l15 = lane & 15, lh = lane >> 4;
  const int bh = blockIdx.x;
  const ushort_t* q  = qb  + (size_t)bh * 4096;
  const ushort_t* k  = kb  + (size_t)bh * 4096;
  const ushort_t* vT = vtb + (size_t)bh * 4096;

  if (tid < 225) C0s[tid] = C0[tid];

  // ---- Phase 1: all MFMA for logits; wave-own stores + scatter2 -----------
  short8 qf[2];
#pragma unroll
  for (int kh = 0; kh < 2; ++kh)
    qf[kh] = *(const short8*)(q + (wid*16 + l15)*64 + kh*32 + lh*8);

  f32x4 acc1[4] = {};
#pragma unroll
  for (int kh = 0; kh < 2; ++kh)
#pragma unroll
    for (int ni = 0; ni < 4; ++ni) {
      short8 b = *(const short8*)(k + (ni*16 + l15)*64 + kh*32 + lh*8);
      acc1[ni] = __builtin_amdgcn_mfma_f32_16x16x32_bf16(qf[kh], b, acc1[ni], 0,0,0);
    }
  {
    f32x4 acc2[15] = {};
#pragma unroll
    for (int kh = 0; kh < 2; ++kh)
#pragma unroll
      for (int nc = 0; nc < 15; ++nc) {
        short8 b = *(const short8*)(rkp + (nc*16 + l15)*64 + kh*32 + lh*8);
        acc2[nc] = __builtin_amdgcn_mfma_f32_16x16x32_bf16(qf[kh], b, acc2[nc], 0,0,0);
      }
    // store acc1 (wave-own rows)
#pragma unroll
    for (int ni = 0; ni < 4; ++ni)
#pragma unroll
      for (int r = 0; r < 4; ++r)
        logits[(wid*16 + lh*4 + r)*65 + ni*16 + l15] = acc1[ni][r];
    // scatter acc2 (wave-own rows; same-wave LDS order after stores)
#pragma unroll
    for (int nc = 0; nc < 15; ++nc) {
      const int rr = nc*16 + l15;
      const int dx = rr / 15, dy = rr - dx*15;
#pragma unroll
      for (int r = 0; r < 4; ++r) {
        const int i = wid*16 + lh*4 + r;
        const int xj = (i >> 3) - dx + 7, yj = (i & 7) - dy + 7;
        if ((unsigned)xj < 8u && (unsigned)yj < 8u)
          logits[i*65 + xj*8 + yj] += acc2[nc][r];
      }
    }
  }
  // acc3 = k @ rel_q^T
  f32x4 acc3[15] = {};
  {
    short8 kf[2];
#pragma unroll
    for (int kh = 0; kh < 2; ++kh)
      kf[kh] = *(const short8*)(k + (wid*16 + l15)*64 + kh*32 + lh*8);
#pragma unroll
    for (int kh = 0; kh < 2; ++kh)
#pragma unroll
      for (int nc = 0; nc < 15; ++nc) {
        short8 b = *(const short8*)(rqp + (nc*16 + l15)*64 + kh*32 + lh*8);
        acc3[nc] = __builtin_amdgcn_mfma_f32_16x16x32_bf16(kf[kh], b, acc3[nc], 0,0,0);
      }
  }
  __syncthreads();  // BAR1: all stores+scatter2 done

  // ---- Phase 2: scatter acc3 (cross-wave rows) -----------------------------
#pragma unroll
  for (int nc = 0; nc < 15; ++nc) {
    const int rr = nc*16 + l15;
    const int dx = rr / 15, dy = rr - dx*15;
#pragma unroll
    for (int r = 0; r < 4; ++r) {
      const int j = wid*16 + lh*4 + r;
      const int xi = (j >> 3) + dx - 7, yi = (j & 7) + dy - 7;
      if ((unsigned)xi < 8u && (unsigned)yi < 8u)
        logits[(xi*8 + yi)*65 + j] += acc3[nc][r];
    }
  }
  __syncthreads();  // BAR2: logits complete

  // ---- Phase 3: softmax; then (after BAR3) write attnS + S over logits ----
  const int i = tid >> 2, qq = tid & 3;
  {
    const int xi8 = i >> 3, yi8 = i & 7;
    float vals[16]; int rrv[16];
    float m = -1e30f;
#pragma unroll
    for (int jj = 0; jj < 16; ++jj) {
      const int j = qq*16 + jj;
      const int rr = (xi8 - (j>>3) + 7)*15 + (yi8 - (j&7) + 7);
      rrv[jj] = rr;
      float v = (logits[i*65 + j] + C0s[rr]) * 0.125f;
      vals[jj] = v; m = fmaxf(m, v);
    }
    m = fmaxf(m, __shfl_xor(m, 1));
    m = fmaxf(m, __shfl_xor(m, 2));
    float s = 0;
#pragma unroll
    for (int jj = 0; jj < 16; ++jj) { float e = __expf(vals[jj]-m); vals[jj] = e; s += e; }
    s += __shfl_xor(s, 1); s += __shfl_xor(s, 2);
    const float inv = 1.0f / s;
    ushort_t pv[16];
#pragma unroll
    for (int jj = 0; jj < 16; ++jj) pv[jj] = f2bf(vals[jj]*inv);

    __syncthreads();  // BAR3: all logits/C0 reads done; S/attnS writes may begin

    // zero my slice of S (swizzled granules land on same footprint)
    short8 z = {};
#pragma unroll
    for (int g = 0; g < 8; ++g)
      *(short8*)(Sb + i*512 + (((qq*8 + g) ^ (i&7)) << 4)) = z;
    // packed attnS rows (2 x 16B per thread covers the row with 4 threads)
    ushort8 w0, w1;
#pragma unroll
    for (int e = 0; e < 8; ++e) { w0[e] = pv[e]; w1[e] = pv[8+e]; }
    *(ushort8*)(attnSB + i*128 + (((2*qq)   ^ (i&7)) << 4)) = w0;
    *(ushort8*)(attnSB + i*128 + (((2*qq+1) ^ (i&7)) << 4)) = w1;
    // scatter S (same-wave LDS order after zeros)
#pragma unroll
    for (int jj = 0; jj < 16; ++jj) {
      const int rr = rrv[jj];
      *(ushort_t*)(Sb + i*512 + (((rr>>3) ^ (i&7)) << 4) + ((rr&7) << 1)) = pv[jj];
    }
  }
  // no barrier: P5 reads only wave-own rows of attnS/S

  // ---- Phase 4: out = attn @ v + S @ rel_v^T -------------------------------
  {
    f32x4 acco[4] = {};
    const int row = wid*16 + l15;
#pragma unroll
    for (int kh = 0; kh < 2; ++kh) {
      const int g = kh*4 + lh;
      short8 a = *(const short8*)(attnSB + row*128 + ((g ^ (row&7)) << 4));
#pragma unroll
      for (int ni = 0; ni < 4; ++ni) {
        short8 b = *(const short8*)(vT + (ni*16 + l15)*64 + kh*32 + lh*8);
        acco[ni] = __builtin_amdgcn_mfma_f32_16x16x32_bf16(a, b, acco[ni], 0,0,0);
      }
    }
#pragma unroll
    for (int ks = 0; ks < 8; ++ks) {
      const int g = ks*4 + lh;
      short8 a = *(const short8*)(Sb + row*512 + ((g ^ (row&7)) << 4));
#pragma unroll
      for (int ni = 0; ni < 4; ++ni) {
        short8 b = *(const short8*)(rvT + (ni*16 + l15)*256 + ks*32 + lh*8);
        acco[ni] = __builtin_amdgcn_mfma_f32_16x16x32_bf16(a, b, acco[ni], 0,0,0);
      }
    }
    const int b_idx = bh >> 3, hh = bh & 7;
#pragma unroll
    for (int ni = 0; ni < 4; ++ni)
#pragma unroll
      for (int r = 0; r < 4; ++r) {
        const int ii = wid*16 + lh*4 + r;
        const int d = ni*16 + l15;
        attn_out[((size_t)(b_idx*64 + ii))*512 + hh*64 + d] = f2bf(acco[ni][r]);
      }
  }
}

// ---------------------------------------------------------------------------
extern "C" void kernel_launch(void* const* d_in, const int* in_sizes, int n_in,
                              void* d_out, int out_size, void* d_ws, size_t ws_size,
                              hipStream_t stream)
{
  (void)in_sizes; (void)n_in; (void)out_size; (void)ws_size;
  const float* x     = (const float*)d_in[0];
  const float* w_qkv = (const float*)d_in[1];
  const float* w_proj= (const float*)d_in[2];
  const float* b_proj= (const float*)d_in[3];
  const float* w1    = (const float*)d_in[4];
  const float* b1    = (const float*)d_in[5];
  const float* w2    = (const float*)d_in[6];
  const float* b2    = (const float*)d_in[7];
  const float* g1    = (const float*)d_in[8];
  const float* be1   = (const float*)d_in[9];
  const float* g2    = (const float*)d_in[10];
  const float* be2   = (const float*)d_in[11];
  const float* rel_q = (const float*)d_in[12];
  const float* rel_k = (const float*)d_in[13];
  const float* rel_v = (const float*)d_in[14];

  char* ws = (char*)d_ws;
  const size_t MB = 1ull << 20;
  ushort_t* h      = (ushort_t*)(ws);            // 32MiB (reused as h2)
  ushort_t* qb     = (ushort_t*)(ws + 32*MB);
  ushort_t* kb     = (ushort_t*)(ws + 64*MB);
  ushort_t* vtb    = (ushort_t*)(ws + 96*MB);
  ushort_t* attn_o = (ushort_t*)(ws + 128*MB);
  ushort_t* ff     = (ushort_t*)(ws + 32*MB);    // aliases qb..attn_o (dead)
  float*    x_mid  = (float*)(ws + 160*MB);      // 64MiB
  char* wreg = ws + 224*MB;
  ushort_t* wqkvT = (ushort_t*)(wreg);
  ushort_t* wprojT= (ushort_t*)(wreg + 1572864);
  ushort_t* w1T   = (ushort_t*)(wreg + 2097152);
  ushort_t* w2T   = (ushort_t*)(wreg + 4194304);
  ushort_t* rkp   = (ushort_t*)(wreg + 6291456);
  ushort_t* rqp   = (ushort_t*)(wreg + 6322176);
  ushort_t* rvT   = (ushort_t*)(wreg + 6352896);
  float*    C0    = (float*)(wreg + 6385664);

  wt_kernel<<<(512*1536+255)/256, 256, 0, stream>>>(w_qkv, wqkvT, 512, 1536);
  wt_kernel<<<(512*512+255)/256, 256, 0, stream>>>(w_proj, wprojT, 512, 512);
  wt_kernel<<<(512*2048+255)/256, 256, 0, stream>>>(w1, w1T, 512, 2048);
  wt_kernel<<<(2048*512+255)/256, 256, 0, stream>>>(w2, w2T, 2048, 512);
  prep_rel_kernel<<<64, 256, 0, stream>>>(rel_q, rel_k, rel_v, rqp, rkp, rvT, C0);

  ln_kernel<<<8192, 256, 0, stream>>>(x, g1, be1, h);
  gemm_kernel<0><<<dim3(256,12), 256, 0, stream>>>(h, wqkvT, 32768, 1536, 512,
      nullptr, nullptr, nullptr, nullptr, qb, kb, vtb);
  attn_kernel<<<4096, 256, 0, stream>>>(qb, kb, vtb, rkp, rqp, rvT, C0, attn_o);
  gemm_kernel<1><<<dim3(256,4), 256, 0, stream>>>(attn_o, wprojT, 32768, 512, 512,
      b_proj, x, x_mid, nullptr, nullptr, nullptr, nullptr);
  ln_kernel<<<8192, 256, 0, stream>>>(x_mid, g2, be2, h);
  gemm_kernel<2><<<dim3(256,16), 256, 0, stream>>>(h, w1T, 32768, 2048, 512,
      b1, nullptr, nullptr, ff, nullptr, nullptr, nullptr);
  gemm_kernel<3><<<dim3(256,4), 256, 0, stream>>>(ff, w2T, 32768, 512, 2048,
      b2, x_mid, (float*)d_out, nullptr, nullptr, nullptr, nullptr);
}